// Round 1
// baseline (128.337 us; speedup 1.0000x reference)
//
#include <hip/hip_runtime.h>
#include <hip/hip_cooperative_groups.h>
#include <math.h>

namespace cg = cooperative_groups;

#define ALPHA 0.2f

constexpr int N = 1024;
constexpr int C = 32;

// ---------------------------------------------------------------------------
// Fused single cooperative kernel (512 blocks x 256 threads):
//   stage 0: each block computes 8 of the 4096 exp(score) values
//            (u[b,n] / v[b,j] dot products; same mapping as old uvexp_kernel)
//   adj prefetch: the 16 adj values/thread are loaded into registers BEFORE
//            the grid sync, so the 8.4 MB adj HBM stream overlaps the barrier
//   grid.sync()
//   stage 1/2: former attn_kernel4 body (4 output rows per block), reading
//            eu/ev from workspace and adj from registers.
// Rationale: work floor is ~5 us (adj 8.4 MB -> 1.3 us, 0.134 GFLOP -> <1 us);
// measured 78 us is dominated by the dependent two-launch structure, so the
// remaining lever is removing the second dispatch + drain/ramp.
// ---------------------------------------------------------------------------
__global__ __launch_bounds__(256) void fused_gat_kernel(
    const float* __restrict__ x, const int* __restrict__ adj,
    const float* __restrict__ W2, const float* __restrict__ a,
    const float* __restrict__ bias, float* __restrict__ eu,
    float* __restrict__ ev, float* __restrict__ out)
{
    __shared__ float swT[1024 * 4];      // [j][r]
    __shared__ float partF[4 * 4 * 32];  // [wave][r][c]
    __shared__ float wsred[4 * 4];       // [wave][r]

    const int tid = threadIdx.x;

    // ---- stage 0: 8 exp(score) values per block (32 lanes per value) ----
    // W2/a read straight from global (8 KB, L2-hot; coalesced across e-lanes).
    {
        const int gout = blockIdx.x * 8 + (tid >> 5);  // 0..4095
        const int e = tid & 31;
        const int isV = gout >> 11;      // 0 -> u, 1 -> v
        const int idx = gout & 2047;     // b*1024 + n
        const int b = idx >> 10;
        const int n = idx & 1023;
        const float* xb = x + b * (N * C);

        float acc = 0.f;
        if (!isV) {
            const float* xr = xb + n * 32;
            #pragma unroll
            for (int c = 0; c < 32; ++c) {
                const float xv = xr[c];
                acc = fmaf(xv, W2[c * 32 + e], acc);
                acc = fmaf(xv, W2[(c + 32) * 32 + e], acc);
            }
        } else {
            const float* x0 = xb + ((2 * n) & 1023) * 32;
            const float* x1 = xb + ((2 * n + 1) & 1023) * 32;
            #pragma unroll
            for (int c = 0; c < 32; ++c) {
                acc = fmaf(x0[c], W2[c * 32 + e], acc);
                acc = fmaf(x1[c], W2[(c + 32) * 32 + e], acc);
            }
        }
        float t = (acc > 0.f ? acc : ALPHA * acc) * a[e];
        #pragma unroll
        for (int m = 16; m >= 1; m >>= 1) t += __shfl_xor(t, m);
        if (e == 0) (isV ? ev : eu)[idx] = expf(t);
    }

    // ---- adj prefetch into registers: overlaps the grid-sync wait ----
    const int row0 = blockIdx.x * 4;     // 4 rows: row0..row0+3
    const int b = row0 >> 10;
    const int i0 = row0 & 1023;
    const int wave = tid >> 6;
    const int lane = tid & 63;

    int aij[4][4];                       // [m][r]
    #pragma unroll
    for (int m = 0; m < 4; ++m) {
        #pragma unroll
        for (int r = 0; r < 4; ++r)
            aij[m][r] = adj[(size_t)(row0 + r) * 1024 + tid + 256 * m];
    }

    cg::this_grid().sync();

    // ---- stage 1: masked weights, thread owns j = tid + 256m ----
    float w[4][4];                       // [m][r]
    if (i0 < 512) {
        float su[4][2];
        #pragma unroll
        for (int r = 0; r < 4; ++r) {
            su[r][0] = eu[(b << 10) + 2 * (i0 + r)];
            su[r][1] = eu[(b << 10) + 2 * (i0 + r) + 1];
        }
        #pragma unroll
        for (int m = 0; m < 4; ++m) {
            const int half = m >> 1;     // j>=512 <=> m>=2
            #pragma unroll
            for (int r = 0; r < 4; ++r)
                w[m][r] = aij[m][r] > 0 ? su[r][half] : 0.f;
        }
    } else {
        #pragma unroll
        for (int m = 0; m < 4; ++m) {
            const float evj = ev[(b << 10) + tid + 256 * m];
            #pragma unroll
            for (int r = 0; r < 4; ++r)
                w[m][r] = aij[m][r] > 0 ? evj : 0.f;
        }
    }
    float ws[4];
    #pragma unroll
    for (int r = 0; r < 4; ++r)
        ws[r] = (w[0][r] + w[1][r]) + (w[2][r] + w[3][r]);
    #pragma unroll
    for (int m = 0; m < 4; ++m)
        ((float4*)swT)[tid + 256 * m] = make_float4(w[m][0], w[m][1], w[m][2], w[m][3]);
    #pragma unroll
    for (int s = 32; s >= 1; s >>= 1) {
        ws[0] += __shfl_xor(ws[0], s);
        ws[1] += __shfl_xor(ws[1], s);
        ws[2] += __shfl_xor(ws[2], s);
        ws[3] += __shfl_xor(ws[3], s);
    }
    if (lane == 0) {
        #pragma unroll
        for (int r = 0; r < 4; ++r) wsred[wave * 4 + r] = ws[r];
    }
    __syncthreads();

    // ---- stage 2: weighted sums, x float4 reused across 4 rows ----
    const float4* x4 = (const float4*)(x + b * (N * C)); // x4[j*8 + c4]
    const int c4 = tid & 7;
    const int jg = tid >> 3;             // 0..31, 32 j's each
    float4 a0 = make_float4(0.f, 0.f, 0.f, 0.f);
    float4 a1 = a0, a2 = a0, a3 = a0;
    #pragma unroll 8
    for (int q = 0; q < 32; ++q) {
        const int j = jg * 32 + ((q + jg) & 31);
        const float4 wv = ((const float4*)swT)[j];
        const float4 xv = x4[j * 8 + c4];
        a0.x = fmaf(wv.x, xv.x, a0.x); a0.y = fmaf(wv.x, xv.y, a0.y);
        a0.z = fmaf(wv.x, xv.z, a0.z); a0.w = fmaf(wv.x, xv.w, a0.w);
        a1.x = fmaf(wv.y, xv.x, a1.x); a1.y = fmaf(wv.y, xv.y, a1.y);
        a1.z = fmaf(wv.y, xv.z, a1.z); a1.w = fmaf(wv.y, xv.w, a1.w);
        a2.x = fmaf(wv.z, xv.x, a2.x); a2.y = fmaf(wv.z, xv.y, a2.y);
        a2.z = fmaf(wv.z, xv.z, a2.z); a2.w = fmaf(wv.z, xv.w, a2.w);
        a3.x = fmaf(wv.w, xv.x, a3.x); a3.y = fmaf(wv.w, xv.y, a3.y);
        a3.z = fmaf(wv.w, xv.z, a3.z); a3.w = fmaf(wv.w, xv.w, a3.w);
    }
    // wave-reduce over the 8 jg-groups (lane bits 3..5)
    #pragma unroll
    for (int s = 8; s <= 32; s <<= 1) {
        a0.x += __shfl_xor(a0.x, s); a0.y += __shfl_xor(a0.y, s);
        a0.z += __shfl_xor(a0.z, s); a0.w += __shfl_xor(a0.w, s);
        a1.x += __shfl_xor(a1.x, s); a1.y += __shfl_xor(a1.y, s);
        a1.z += __shfl_xor(a1.z, s); a1.w += __shfl_xor(a1.w, s);
        a2.x += __shfl_xor(a2.x, s); a2.y += __shfl_xor(a2.y, s);
        a2.z += __shfl_xor(a2.z, s); a2.w += __shfl_xor(a2.w, s);
        a3.x += __shfl_xor(a3.x, s); a3.y += __shfl_xor(a3.y, s);
        a3.z += __shfl_xor(a3.z, s); a3.w += __shfl_xor(a3.w, s);
    }
    if (lane < 8) {
        ((float4*)partF)[(wave * 4 + 0) * 8 + c4] = a0;
        ((float4*)partF)[(wave * 4 + 1) * 8 + c4] = a1;
        ((float4*)partF)[(wave * 4 + 2) * 8 + c4] = a2;
        ((float4*)partF)[(wave * 4 + 3) * 8 + c4] = a3;
    }
    __syncthreads();

    // ---- tail: 128 threads = 4 rows x 32 channels ----
    if (tid < 128) {
        const int r = tid >> 5, c = tid & 31;
        float o = (partF[(0 * 4 + r) * 32 + c] + partF[(1 * 4 + r) * 32 + c]) +
                  (partF[(2 * 4 + r) * 32 + c] + partF[(3 * 4 + r) * 32 + c]);
        float dn = (wsred[0 * 4 + r] + wsred[1 * 4 + r]) +
                   (wsred[2 * 4 + r] + wsred[3 * 4 + r]);
        if (dn == 0.f) {
            // all-masked row: reference softmax degenerates to uniform 1/N
            o = 0.f;
            for (int j = 0; j < 1024; ++j) o += x[b * (N * C) + j * 32 + c];
            dn = 1024.f;
        }
        out[(size_t)(row0 + r) * 32 + c] = tanhf(fmaf(o, 1.0f / dn, bias[c]));
    }
}

extern "C" void kernel_launch(void* const* d_in, const int* in_sizes, int n_in,
                              void* d_out, int out_size, void* d_ws, size_t ws_size,
                              hipStream_t stream) {
    const float* x    = (const float*)d_in[0];
    const int*   adj  = (const int*)d_in[1];
    // d_in[2] = W1: dead code in the reference, unused
    const float* W2   = (const float*)d_in[3];
    const float* a    = (const float*)d_in[4];
    const float* bias = (const float*)d_in[5];
    float* out = (float*)d_out;

    float* eu = (float*)d_ws;      // 2*1024 floats
    float* ev = eu + 2 * 1024;     // 2*1024 floats

    void* args[] = {(void*)&x, (void*)&adj, (void*)&W2, (void*)&a,
                    (void*)&bias, (void*)&eu, (void*)&ev, (void*)&out};
    hipLaunchCooperativeKernel((const void*)fused_gat_kernel,
                               dim3(512), dim3(256), args, 0, stream);
}

// Round 2
// 85.123 us; speedup vs baseline: 1.5077x; 1.5077x over previous
//
#include <hip/hip_runtime.h>
#include <math.h>

#define ALPHA 0.2f

constexpr int N = 1024;
constexpr int C = 32;
constexpr int R = 8;    // rows per block
constexpr int T = 512;  // threads per block

// ---------------------------------------------------------------------------
// Single standard launch, 256 blocks x 512 threads, 8 output rows per block.
// No inter-block dependency:
//   - rows i<512 ("producer" blocks) need eu[2i+h] only for their own 8 rows
//     -> 16 values, computed locally (16 score-units x 32 lanes).
//   - rows i>=512 ("consumer" blocks) need ev[j]; but ev[j] = ev[j & 511]
//     (x-pair (2j)%N,(2j+1)%N has period 512), so each block recomputes the
//     512 distinct values locally: 1 thread per j, 2048 fma each (~3.4 us).
//   - the 16 adj values/thread are prefetched into registers BEFORE the
//     pre-phase so the 8.4 MB adj HBM stream hides under the fma work.
// This removes the second launch AND the grid sync (round-1 coop experiment:
// 41.5 us dispatch with 90% spin + ~46 us launch overhead -> abandoned).
// ---------------------------------------------------------------------------
__global__ __launch_bounds__(T) void gat_fused(
    const float* __restrict__ x, const int* __restrict__ adj,
    const float* __restrict__ W2, const float* __restrict__ a,
    const float* __restrict__ bias, float* __restrict__ out)
{
    __shared__ float sW2[64 * 32];     // 8 KB
    __shared__ float sa[32];
    __shared__ float sev[512];         // consumer: ev[0..511]; producer: [0..15] = eu
    __shared__ float swT[1024 * R];    // 32 KB, [j][r]
    __shared__ float partF[8 * R * 32];// 8 KB, [wave][r][c]
    __shared__ float wsred[8 * R];     // [wave][r]

    const int tid = threadIdx.x;
    const int row0 = blockIdx.x * R;   // global row = b*1024 + i
    const int b = row0 >> 10;
    const int i0 = row0 & 1023;
    const int wave = tid >> 6;
    const int lane = tid & 63;
    const float* xb = x + b * (N * C);

    // ---- adj prefetch into registers (overlaps pre-phase compute) ----
    int aij[2][R];
    #pragma unroll
    for (int h = 0; h < 2; ++h)
        #pragma unroll
        for (int r = 0; r < R; ++r)
            aij[h][r] = adj[(size_t)(row0 + r) * 1024 + tid + 512 * h];

    // ---- stage W2 (both 32-row halves) and a ----
    #pragma unroll
    for (int k = 0; k < 4; ++k) sW2[tid + 512 * k] = W2[tid + 512 * k];
    if (tid < 32) sa[tid] = a[tid];
    __syncthreads();

    // ---- pre-phase: local score exponentials ----
    if (i0 < 512) {
        // eu[2*i0 + k], k = 0..15 : 16 units x 32 lanes
        const int k = tid >> 5;
        const int e = tid & 31;
        const float* xr = xb + (2 * i0 + k) * 32;
        float acc = 0.f;
        #pragma unroll
        for (int c2 = 0; c2 < 32; ++c2)
            acc = fmaf(xr[c2], sW2[c2 * 32 + e] + sW2[(c2 + 32) * 32 + e], acc);
        float t = (acc > 0.f ? acc : ALPHA * acc) * sa[e];
        #pragma unroll
        for (int m = 16; m >= 1; m >>= 1) t += __shfl_xor(t, m);
        if (e == 0) sev[k] = expf(t);
    } else {
        // sev[jj] for jj = tid: x rows 2jj, 2jj+1 are 64 contiguous floats
        float z[32];
        #pragma unroll
        for (int e = 0; e < 32; ++e) z[e] = 0.f;
        const float4* x04 = (const float4*)(xb + 2 * tid * 32);
        #pragma unroll
        for (int c4 = 0; c4 < 16; ++c4) {
            const float4 f = x04[c4];
            const int cbase = c4 * 4;
            #pragma unroll
            for (int cc = 0; cc < 4; ++cc) {
                const float xv = (&f.x)[cc];
                const float* wrow = &sW2[(cbase + cc) * 32];
                #pragma unroll
                for (int e = 0; e < 32; ++e) z[e] = fmaf(xv, wrow[e], z[e]);
            }
        }
        float sc = 0.f;
        #pragma unroll
        for (int e = 0; e < 32; ++e) {
            const float tv = z[e] > 0.f ? z[e] : ALPHA * z[e];
            sc = fmaf(tv, sa[e], sc);
        }
        sev[tid] = expf(sc);
    }
    __syncthreads();

    // ---- phase 1: masked weights (thread owns j = tid, tid+512) ----
    float w[2][R];
    if (i0 < 512) {
        #pragma unroll
        for (int h = 0; h < 2; ++h)
            #pragma unroll
            for (int r = 0; r < R; ++r)
                w[h][r] = aij[h][r] > 0 ? sev[2 * r + h] : 0.f;   // eu[2(i0+r)+h]
    } else {
        const float evj = sev[tid];  // ev[tid] == ev[tid+512]
        #pragma unroll
        for (int h = 0; h < 2; ++h)
            #pragma unroll
            for (int r = 0; r < R; ++r)
                w[h][r] = aij[h][r] > 0 ? evj : 0.f;
    }
    #pragma unroll
    for (int h = 0; h < 2; ++h) {
        const int j = tid + 512 * h;
        ((float4*)swT)[j * 2 + 0] = make_float4(w[h][0], w[h][1], w[h][2], w[h][3]);
        ((float4*)swT)[j * 2 + 1] = make_float4(w[h][4], w[h][5], w[h][6], w[h][7]);
    }
    float ws[R];
    #pragma unroll
    for (int r = 0; r < R; ++r) ws[r] = w[0][r] + w[1][r];
    #pragma unroll
    for (int s = 32; s >= 1; s >>= 1) {
        #pragma unroll
        for (int r = 0; r < R; ++r) ws[r] += __shfl_xor(ws[r], s);
    }
    if (lane == 0) {
        #pragma unroll
        for (int r = 0; r < R; ++r) wsred[wave * R + r] = ws[r];
    }
    __syncthreads();

    // ---- phase 2: weighted x sums; x float4 reused across 8 rows ----
    const float4* x4 = (const float4*)xb;          // x4[j*8 + c4]
    const int c4 = tid & 7;
    const int jg = tid >> 3;                       // 0..63, 16 j's each
    float4 acc[R];
    #pragma unroll
    for (int r = 0; r < R; ++r) acc[r] = make_float4(0.f, 0.f, 0.f, 0.f);
    #pragma unroll 4
    for (int q = 0; q < 16; ++q) {
        const int j = jg * 16 + q;
        const float4 w0 = ((const float4*)swT)[j * 2 + 0];
        const float4 w1 = ((const float4*)swT)[j * 2 + 1];
        const float4 xv = x4[j * 8 + c4];
        acc[0].x = fmaf(w0.x, xv.x, acc[0].x); acc[0].y = fmaf(w0.x, xv.y, acc[0].y);
        acc[0].z = fmaf(w0.x, xv.z, acc[0].z); acc[0].w = fmaf(w0.x, xv.w, acc[0].w);
        acc[1].x = fmaf(w0.y, xv.x, acc[1].x); acc[1].y = fmaf(w0.y, xv.y, acc[1].y);
        acc[1].z = fmaf(w0.y, xv.z, acc[1].z); acc[1].w = fmaf(w0.y, xv.w, acc[1].w);
        acc[2].x = fmaf(w0.z, xv.x, acc[2].x); acc[2].y = fmaf(w0.z, xv.y, acc[2].y);
        acc[2].z = fmaf(w0.z, xv.z, acc[2].z); acc[2].w = fmaf(w0.z, xv.w, acc[2].w);
        acc[3].x = fmaf(w0.w, xv.x, acc[3].x); acc[3].y = fmaf(w0.w, xv.y, acc[3].y);
        acc[3].z = fmaf(w0.w, xv.z, acc[3].z); acc[3].w = fmaf(w0.w, xv.w, acc[3].w);
        acc[4].x = fmaf(w1.x, xv.x, acc[4].x); acc[4].y = fmaf(w1.x, xv.y, acc[4].y);
        acc[4].z = fmaf(w1.x, xv.z, acc[4].z); acc[4].w = fmaf(w1.x, xv.w, acc[4].w);
        acc[5].x = fmaf(w1.y, xv.x, acc[5].x); acc[5].y = fmaf(w1.y, xv.y, acc[5].y);
        acc[5].z = fmaf(w1.y, xv.z, acc[5].z); acc[5].w = fmaf(w1.y, xv.w, acc[5].w);
        acc[6].x = fmaf(w1.z, xv.x, acc[6].x); acc[6].y = fmaf(w1.z, xv.y, acc[6].y);
        acc[6].z = fmaf(w1.z, xv.z, acc[6].z); acc[6].w = fmaf(w1.z, xv.w, acc[6].w);
        acc[7].x = fmaf(w1.w, xv.x, acc[7].x); acc[7].y = fmaf(w1.w, xv.y, acc[7].y);
        acc[7].z = fmaf(w1.w, xv.z, acc[7].z); acc[7].w = fmaf(w1.w, xv.w, acc[7].w);
    }
    // reduce over the 8 jg-subgroups within the wave (lane bits 3..5)
    #pragma unroll
    for (int s = 8; s <= 32; s <<= 1) {
        #pragma unroll
        for (int r = 0; r < R; ++r) {
            acc[r].x += __shfl_xor(acc[r].x, s);
            acc[r].y += __shfl_xor(acc[r].y, s);
            acc[r].z += __shfl_xor(acc[r].z, s);
            acc[r].w += __shfl_xor(acc[r].w, s);
        }
    }
    if (lane < 8) {
        #pragma unroll
        for (int r = 0; r < R; ++r)
            ((float4*)partF)[(wave * R + r) * 8 + c4] = acc[r];
    }
    __syncthreads();

    // ---- tail: 256 threads = 8 rows x 32 channels ----
    if (tid < 256) {
        const int r = tid >> 5, c = tid & 31;
        float o = 0.f, dn = 0.f;
        #pragma unroll
        for (int wv = 0; wv < 8; ++wv) {
            o  += partF[(wv * R + r) * 32 + c];
            dn += wsred[wv * R + r];
        }
        if (dn == 0.f) {
            // all-masked row: reference softmax degenerates to uniform 1/N
            o = 0.f;
            for (int j = 0; j < 1024; ++j) o += xb[j * 32 + c];
            dn = 1024.f;
        }
        out[(size_t)(row0 + r) * 32 + c] = tanhf(fmaf(o, 1.0f / dn, bias[c]));
    }
}

extern "C" void kernel_launch(void* const* d_in, const int* in_sizes, int n_in,
                              void* d_out, int out_size, void* d_ws, size_t ws_size,
                              hipStream_t stream) {
    const float* x    = (const float*)d_in[0];
    const int*   adj  = (const int*)d_in[1];
    // d_in[2] = W1: dead code in the reference, unused
    const float* W2   = (const float*)d_in[3];
    const float* a    = (const float*)d_in[4];
    const float* bias = (const float*)d_in[5];
    float* out = (float*)d_out;

    gat_fused<<<256, T, 0, stream>>>(x, adj, W2, a, bias, out);
}

// Round 3
// 77.711 us; speedup vs baseline: 1.6515x; 1.0954x over previous
//
#include <hip/hip_runtime.h>
#include <math.h>

#define ALPHA 0.2f

constexpr int N = 1024;
constexpr int C = 32;

// ---------------------------------------------------------------------------
// Kernel 1: eu[b,n] = exp(u[b,n]), ev[b,n] = exp(v[b,n])
//   u[b,n] = dot(lrelu(x[b,n] @ (W2a+W2b)), a)
//   v[b,j] = dot(lrelu(x[b,(2j)%N] @ W2a + x[b,(2j+1)%N] @ W2b), a)
// Scores are O(1) (x~N(0,1), W2,a~0.1N) so unshifted exp is safe in f32;
// softmax shift-invariance removes all per-row max reductions downstream.
// W2/a are read straight from global: the pattern W2[c*32+e] is 32
// consecutive floats per 32-lane unit (coalesced, L1-resident, 8 KB total),
// so the former LDS staging pass + __syncthreads was pure overhead.
// ---------------------------------------------------------------------------
__global__ __launch_bounds__(256) void uvexp_kernel(
    const float* __restrict__ x, const float* __restrict__ W2,
    const float* __restrict__ a, float* __restrict__ eu, float* __restrict__ ev)
{
    const int tid = threadIdx.x;
    const int gout = (blockIdx.x * 256 + tid) >> 5;  // 0..4095
    const int e = tid & 31;
    const int isV = gout >> 11;      // 0 -> u, 1 -> v  (block-uniform)
    const int idx = gout & 2047;     // b*1024 + n
    const int b = idx >> 10;
    const int n = idx & 1023;
    const float* xb = x + b * (N * C);

    float acc = 0.f;
    if (!isV) {
        const float* xr = xb + n * 32;
        #pragma unroll
        for (int c = 0; c < 32; ++c) {
            const float xv = xr[c];
            acc = fmaf(xv, W2[c * 32 + e], acc);
            acc = fmaf(xv, W2[(c + 32) * 32 + e], acc);
        }
    } else {
        const float* x0 = xb + ((2 * n) & 1023) * 32;
        const float* x1 = xb + ((2 * n + 1) & 1023) * 32;
        #pragma unroll
        for (int c = 0; c < 32; ++c) {
            acc = fmaf(x0[c], W2[c * 32 + e], acc);
            acc = fmaf(x1[c], W2[(c + 32) * 32 + e], acc);
        }
    }
    float t = (acc > 0.f ? acc : ALPHA * acc) * a[e];
    #pragma unroll
    for (int m = 16; m >= 1; m >>= 1) t += __shfl_xor(t, m);
    if (e == 0) (isV ? ev : eu)[idx] = expf(t);
}

// ---------------------------------------------------------------------------
// Kernel 2: one block per FOUR output rows (same b; 4 | 512 so the i<512
// branch is block-uniform). Register-level x reuse: each x float4 is loaded
// once and applied to 4 row-accumulators -> x L2 traffic drops 4x (268->67MB).
// Weights stored transposed swT[j][r] so the main loop fetches all 4 rows'
// weights in ONE ds_read_b128; rotation (q+jg)&31 keeps j%8 distinct across
// the wave's 8 jg-groups -> conflict-free b128 reads.
// wsum computed in phase 1 (thread-local + wave shuffle), not in the hot loop.
// ---------------------------------------------------------------------------
__global__ __launch_bounds__(256) void attn_kernel4(
    const float* __restrict__ x, const int* __restrict__ adj,
    const float* __restrict__ eu, const float* __restrict__ ev,
    const float* __restrict__ bias, float* __restrict__ out)
{
    __shared__ float swT[1024 * 4];      // [j][r]
    __shared__ float partF[4 * 4 * 32];  // [wave][r][c]
    __shared__ float wsred[4 * 4];       // [wave][r]

    const int tid = threadIdx.x;
    const int row0 = blockIdx.x * 4;     // 4 rows: row0..row0+3
    const int b = row0 >> 10;
    const int i0 = row0 & 1023;
    const int wave = tid >> 6;
    const int lane = tid & 63;

    // ---- phase 1: masked weights, thread owns j = tid + 256m ----
    float w[4][4];                       // [m][r]
    if (i0 < 512) {
        float su[4][2];
        #pragma unroll
        for (int r = 0; r < 4; ++r) {
            su[r][0] = eu[(b << 10) + 2 * (i0 + r)];
            su[r][1] = eu[(b << 10) + 2 * (i0 + r) + 1];
        }
        #pragma unroll
        for (int m = 0; m < 4; ++m) {
            const int half = m >> 1;     // j>=512 <=> m>=2
            #pragma unroll
            for (int r = 0; r < 4; ++r) {
                const int aij = adj[(size_t)(row0 + r) * 1024 + tid + 256 * m];
                w[m][r] = aij > 0 ? su[r][half] : 0.f;
            }
        }
    } else {
        #pragma unroll
        for (int m = 0; m < 4; ++m) {
            const float evj = ev[(b << 10) + tid + 256 * m];
            #pragma unroll
            for (int r = 0; r < 4; ++r) {
                const int aij = adj[(size_t)(row0 + r) * 1024 + tid + 256 * m];
                w[m][r] = aij > 0 ? evj : 0.f;
            }
        }
    }
    float ws[4];
    #pragma unroll
    for (int r = 0; r < 4; ++r)
        ws[r] = (w[0][r] + w[1][r]) + (w[2][r] + w[3][r]);
    #pragma unroll
    for (int m = 0; m < 4; ++m)
        ((float4*)swT)[tid + 256 * m] = make_float4(w[m][0], w[m][1], w[m][2], w[m][3]);
    #pragma unroll
    for (int s = 32; s >= 1; s >>= 1) {
        ws[0] += __shfl_xor(ws[0], s);
        ws[1] += __shfl_xor(ws[1], s);
        ws[2] += __shfl_xor(ws[2], s);
        ws[3] += __shfl_xor(ws[3], s);
    }
    if (lane == 0) {
        #pragma unroll
        for (int r = 0; r < 4; ++r) wsred[wave * 4 + r] = ws[r];
    }
    __syncthreads();

    // ---- phase 2: weighted sums, x float4 reused across 4 rows ----
    const float4* x4 = (const float4*)(x + b * (N * C)); // x4[j*8 + c4]
    const int c4 = tid & 7;
    const int jg = tid >> 3;             // 0..31, 32 j's each
    float4 a0 = make_float4(0.f, 0.f, 0.f, 0.f);
    float4 a1 = a0, a2 = a0, a3 = a0;
    #pragma unroll 8
    for (int q = 0; q < 32; ++q) {
        const int j = jg * 32 + ((q + jg) & 31);
        const float4 wv = ((const float4*)swT)[j];
        const float4 xv = x4[j * 8 + c4];
        a0.x = fmaf(wv.x, xv.x, a0.x); a0.y = fmaf(wv.x, xv.y, a0.y);
        a0.z = fmaf(wv.x, xv.z, a0.z); a0.w = fmaf(wv.x, xv.w, a0.w);
        a1.x = fmaf(wv.y, xv.x, a1.x); a1.y = fmaf(wv.y, xv.y, a1.y);
        a1.z = fmaf(wv.y, xv.z, a1.z); a1.w = fmaf(wv.y, xv.w, a1.w);
        a2.x = fmaf(wv.z, xv.x, a2.x); a2.y = fmaf(wv.z, xv.y, a2.y);
        a2.z = fmaf(wv.z, xv.z, a2.z); a2.w = fmaf(wv.z, xv.w, a2.w);
        a3.x = fmaf(wv.w, xv.x, a3.x); a3.y = fmaf(wv.w, xv.y, a3.y);
        a3.z = fmaf(wv.w, xv.z, a3.z); a3.w = fmaf(wv.w, xv.w, a3.w);
    }
    // wave-reduce over the 8 jg-groups (lane bits 3..5)
    #pragma unroll
    for (int s = 8; s <= 32; s <<= 1) {
        a0.x += __shfl_xor(a0.x, s); a0.y += __shfl_xor(a0.y, s);
        a0.z += __shfl_xor(a0.z, s); a0.w += __shfl_xor(a0.w, s);
        a1.x += __shfl_xor(a1.x, s); a1.y += __shfl_xor(a1.y, s);
        a1.z += __shfl_xor(a1.z, s); a1.w += __shfl_xor(a1.w, s);
        a2.x += __shfl_xor(a2.x, s); a2.y += __shfl_xor(a2.y, s);
        a2.z += __shfl_xor(a2.z, s); a2.w += __shfl_xor(a2.w, s);
        a3.x += __shfl_xor(a3.x, s); a3.y += __shfl_xor(a3.y, s);
        a3.z += __shfl_xor(a3.z, s); a3.w += __shfl_xor(a3.w, s);
    }
    if (lane < 8) {
        ((float4*)partF)[(wave * 4 + 0) * 8 + c4] = a0;
        ((float4*)partF)[(wave * 4 + 1) * 8 + c4] = a1;
        ((float4*)partF)[(wave * 4 + 2) * 8 + c4] = a2;
        ((float4*)partF)[(wave * 4 + 3) * 8 + c4] = a3;
    }
    __syncthreads();

    // ---- tail: 128 threads = 4 rows x 32 channels ----
    if (tid < 128) {
        const int r = tid >> 5, c = tid & 31;
        float o = (partF[(0 * 4 + r) * 32 + c] + partF[(1 * 4 + r) * 32 + c]) +
                  (partF[(2 * 4 + r) * 32 + c] + partF[(3 * 4 + r) * 32 + c]);
        float dn = (wsred[0 * 4 + r] + wsred[1 * 4 + r]) +
                   (wsred[2 * 4 + r] + wsred[3 * 4 + r]);
        if (dn == 0.f) {
            // all-masked row: reference softmax degenerates to uniform 1/N
            o = 0.f;
            for (int j = 0; j < 1024; ++j) o += x[b * (N * C) + j * 32 + c];
            dn = 1024.f;
        }
        out[(size_t)(row0 + r) * 32 + c] = tanhf(fmaf(o, 1.0f / dn, bias[c]));
    }
}

extern "C" void kernel_launch(void* const* d_in, const int* in_sizes, int n_in,
                              void* d_out, int out_size, void* d_ws, size_t ws_size,
                              hipStream_t stream) {
    const float* x    = (const float*)d_in[0];
    const int*   adj  = (const int*)d_in[1];
    // d_in[2] = W1: dead code in the reference, unused
    const float* W2   = (const float*)d_in[3];
    const float* a    = (const float*)d_in[4];
    const float* bias = (const float*)d_in[5];
    float* out = (float*)d_out;

    float* eu = (float*)d_ws;      // 2*1024 floats
    float* ev = eu + 2 * 1024;     // 2*1024 floats

    uvexp_kernel<<<512, 256, 0, stream>>>(x, W2, a, eu, ev);
    attn_kernel4<<<512, 256, 0, stream>>>(x, adj, eu, ev, bias, out);
}